// Round 1
// baseline (58.065 us; speedup 1.0000x reference)
//
#include <hip/hip_runtime.h>
#include <math.h>

#define NN   1024
#define DD   256
#define NCLS 10
#define FEPS 1e-12f

#define TI 64
#define TJ 64
#define DC 64

// quad swizzle: spreads LDS bank-quads for both i-broadcast and j-spread reads
__device__ __forceinline__ int swq(int row, int q) {
    return (q + row + (row >> 2)) & 15;
}

__global__ __launch_bounds__(256) void count_kernel(const long long* __restrict__ tgt,
                                                    int* __restrict__ counts) {
    __shared__ int c[NCLS];
    int tid = threadIdx.x;
    if (tid < NCLS) c[tid] = 0;
    __syncthreads();
    for (int k = tid; k < NN; k += 256) atomicAdd(&c[(int)tgt[k]], 1);
    __syncthreads();
    if (tid < NCLS) counts[tid] = c[tid];
}

__global__ __launch_bounds__(256) void pair_kernel(
    const float* __restrict__ fm_s, const float* __restrict__ fm_t,
    const float* __restrict__ lv, const long long* __restrict__ tgt,
    const int* __restrict__ counts, float* __restrict__ partials)
{
    // 4 x 16KB = 64KB LDS
    __shared__ float Al[TI * DC];
    __shared__ float Bl[TI * DC];
    __shared__ float Vl[TI * DC];
    __shared__ float Fl[TJ * DC];

    const int bid = blockIdx.x;
    const int i0  = (bid >> 4) * TI;
    const int j0  = (bid & 15) * TJ;
    const int tid  = threadIdx.x;
    const int tx   = tid & 15;       // j-group
    const int ty   = tid >> 4;       // i-group
    const int lane = tid & 63;
    const int w    = tid >> 6;       // wave id 0..3
    const int q    = lane >> 2;      // quad within 64-wide d chunk
    const int e    = lane & 3;

    float s1[4][4], s2[4][4];
#pragma unroll
    for (int a = 0; a < 4; ++a)
#pragma unroll
        for (int b = 0; b < 4; ++b) { s1[a][b] = 0.f; s2[a][b] = 0.f; }

    for (int c = 0; c < DD / DC; ++c) {
        __syncthreads();  // previous chunk's reads done before overwrite
        const int dbase = c * DC + lane;

        // stage fm_t tile: wave w handles rows w, w+4, ...
#pragma unroll
        for (int r4 = 0; r4 < TJ; r4 += 4) {
            const int r = r4 + w;
            Fl[r * DC + swq(r, q) * 4 + e] = fm_t[(j0 + r) * DD + dbase];
        }
        // stage student side: A = fs^2*iv + 0.5*lv, B = -2*fs*iv, V = iv
#pragma unroll
        for (int r4 = 0; r4 < TI; r4 += 4) {
            const int r = r4 + w;
            const int g = (i0 + r) * DD + dbase;
            const float fs = fm_s[g];
            const float l  = lv[g];
            const float iv = 1.0f / (2.0f * expf(l) + FEPS);
            const int a = r * DC + swq(r, q) * 4 + e;
            Al[a] = fs * fs * iv + 0.5f * l;
            Bl[a] = -2.0f * fs * iv;
            Vl[a] = iv;
        }
        __syncthreads();

#pragma unroll 2
        for (int dq = 0; dq < DC / 4; ++dq) {
            float4 fa[4], fb[4], fv[4], ff[4];
#pragma unroll
            for (int r = 0; r < 4; ++r) {
                const int i = ty * 4 + r;
                const int o = i * DC + swq(i, dq) * 4;
                fa[r] = *(const float4*)&Al[o];
                fb[r] = *(const float4*)&Bl[o];
                fv[r] = *(const float4*)&Vl[o];
            }
#pragma unroll
            for (int r = 0; r < 4; ++r) {
                const int j = tx * 4 + r;
                ff[r] = *(const float4*)&Fl[j * DC + swq(j, dq) * 4];
            }
#pragma unroll
            for (int rj = 0; rj < 4; ++rj) {
                const float4 f = ff[rj];
                const float4 f2 = make_float4(f.x * f.x, f.y * f.y, f.z * f.z, f.w * f.w);
#pragma unroll
                for (int ri = 0; ri < 4; ++ri) {
                    const float t0 = fmaf(f2.x, fv[ri].x, fmaf(fb[ri].x, f.x, fa[ri].x));
                    const float t1 = fmaf(f2.y, fv[ri].y, fmaf(fb[ri].y, f.y, fa[ri].y));
                    const float t2 = fmaf(f2.z, fv[ri].z, fmaf(fb[ri].z, f.z, fa[ri].z));
                    const float t3 = fmaf(f2.w, fv[ri].w, fmaf(fb[ri].w, f.w, fa[ri].w));
                    s1[ri][rj] += (t0 + t1) + (t2 + t3);
                    s2[ri][rj] += (fabsf(t0) + fabsf(t1)) + (fabsf(t2) + fabsf(t3));
                }
            }
        }
    }

    // epilogue: masked, row-normalized contribution
    float csum = 0.f;
#pragma unroll
    for (int ri = 0; ri < 4; ++ri) {
        const int ti  = (int)tgt[i0 + ty * 4 + ri];
        const int cnt = counts[ti];
        const float wp = 1.0f / (float)cnt;
        const float wn = 1.0f / (float)(NN - cnt);
#pragma unroll
        for (int rj = 0; rj < 4; ++rj) {
            const int tj = (int)tgt[j0 + tx * 4 + rj];
            const float lp = 0.5f * (s2[ri][rj] + s1[ri][rj]);
            const float ln = 0.5f * (s2[ri][rj] - s1[ri][rj]);
            csum += (ti == tj) ? lp * wp : ln * wn;
        }
    }

    // deterministic reduction: wave shuffle, then 4 wave results via LDS (reuse Al)
#pragma unroll
    for (int off = 32; off > 0; off >>= 1) csum += __shfl_down(csum, off);
    __syncthreads();
    if (lane == 0) Al[w] = csum;
    __syncthreads();
    if (tid == 0) partials[bid] = (Al[0] + Al[1]) + (Al[2] + Al[3]);
}

__global__ __launch_bounds__(256) void finalize_kernel(const float* __restrict__ partials,
                                                       float* __restrict__ out) {
    __shared__ float red[256];
    const int tid = threadIdx.x;
    red[tid] = partials[tid];
    __syncthreads();
    for (int s = 128; s > 0; s >>= 1) {
        if (tid < s) red[tid] += red[tid + s];
        __syncthreads();
    }
    if (tid == 0) out[0] = red[0] * (1.0f / (float)NN);
}

extern "C" void kernel_launch(void* const* d_in, const int* in_sizes, int n_in,
                              void* d_out, int out_size, void* d_ws, size_t ws_size,
                              hipStream_t stream) {
    const float* fm_s     = (const float*)d_in[0];
    const float* fm_t     = (const float*)d_in[1];
    const float* lv       = (const float*)d_in[2];
    const long long* tgt  = (const long long*)d_in[3];
    // fusion_true (d_in[4]) == 0 path implemented

    int*   counts   = (int*)d_ws;
    float* partials = (float*)((char*)d_ws + 64);

    hipLaunchKernelGGL(count_kernel, dim3(1), dim3(256), 0, stream, tgt, counts);
    hipLaunchKernelGGL(pair_kernel, dim3(256), dim3(256), 0, stream,
                       fm_s, fm_t, lv, tgt, counts, partials);
    hipLaunchKernelGGL(finalize_kernel, dim3(1), dim3(256), 0, stream,
                       partials, (float*)d_out);
}

// Round 2
// 49.306 us; speedup vs baseline: 1.1777x; 1.1777x over previous
//
#include <hip/hip_runtime.h>
#include <math.h>

#define NN   1024
#define DD   256
#define NCLS 10
#define FEPS 1e-12f

#define TI 64      // i rows per block
#define TJ 128     // j cols per block
#define DC 32      // d chunk staged in LDS
#define DSPLIT 4   // d-range split across blocks
#define NBLK ((NN / TI) * (NN / TJ) * DSPLIT)   // 16*8*4 = 512

// row-dependent quad swizzle (8 quads per 32-float row), bank-verified for
// i-broadcast reads, j-spread reads (2-way), and 2-row staging writes (2-way)
__device__ __forceinline__ int swq8(int r, int q) {
    return (q + r + (r >> 3)) & 7;
}

__global__ __launch_bounds__(256) void count_kernel(const long long* __restrict__ tgt,
                                                    int* __restrict__ counts) {
    __shared__ int c[NCLS];
    int tid = threadIdx.x;
    if (tid < NCLS) c[tid] = 0;
    __syncthreads();
    for (int k = tid; k < NN; k += 256) atomicAdd(&c[(int)tgt[k]], 1);
    __syncthreads();
    if (tid < NCLS) counts[tid] = c[tid];
}

__global__ __launch_bounds__(256) void pair_kernel(
    const float* __restrict__ fm_s, const float* __restrict__ fm_t,
    const float* __restrict__ lv, const long long* __restrict__ tgt,
    const int* __restrict__ counts, float* __restrict__ partials)
{
    // (3*64 + 128) * 32 * 4B = 40 KB  -> 2 blocks/CU
    __shared__ float Al[TI * DC];
    __shared__ float Bl[TI * DC];
    __shared__ float Vl[TI * DC];
    __shared__ float Fl[TJ * DC];

    const int bid  = blockIdx.x;
    const int tile = bid >> 2;        // 0..127
    const int kd   = bid & 3;         // d-quarter
    const int i0   = (tile >> 3) * TI;
    const int j0   = (tile & 7) * TJ;
    const int doff = kd * (DD / DSPLIT);

    const int tid  = threadIdx.x;
    const int tx   = tid & 15;        // j-group: 8 cols each
    const int ty   = tid >> 4;        // i-group: 4 rows each
    const int lane = tid & 63;
    const int w    = tid >> 6;        // wave 0..3
    const int dl   = lane & 31;       // d within chunk
    const int rsub = lane >> 5;       // row-pair select
    const int ql   = dl >> 2;
    const int el   = dl & 3;

    float s1[4][8], s2[4][8];
#pragma unroll
    for (int a = 0; a < 4; ++a)
#pragma unroll
        for (int b = 0; b < 8; ++b) { s1[a][b] = 0.f; s2[a][b] = 0.f; }

    for (int c = 0; c < (DD / DSPLIT) / DC; ++c) {
        __syncthreads();
        const int dbase = doff + c * DC;

        // stage teacher tile: 128 rows, 8 rows per pass (4 waves x 2 rows)
#pragma unroll
        for (int rp = 0; rp < TJ / 8; ++rp) {
            const int r = rp * 8 + w * 2 + rsub;
            Fl[r * DC + swq8(r, ql) * 4 + el] = fm_t[(j0 + r) * DD + dbase + dl];
        }
        // stage student side: A = fs^2*iv + 0.5*lv, B = -2*fs*iv, V = iv
#pragma unroll
        for (int rp = 0; rp < TI / 8; ++rp) {
            const int r = rp * 8 + w * 2 + rsub;
            const int g = (i0 + r) * DD + dbase + dl;
            const float fs = fm_s[g];
            const float l  = lv[g];
            const float iv = 1.0f / (2.0f * expf(l) + FEPS);
            const int  a   = r * DC + swq8(r, ql) * 4 + el;
            const float fsiv = fs * iv;
            Al[a] = fmaf(fsiv, fs, 0.5f * l);
            Bl[a] = -2.0f * fsiv;
            Vl[a] = iv;
        }
        __syncthreads();

#pragma unroll 1
        for (int dq = 0; dq < DC / 4; ++dq) {
            float4 fa[4], fb[4], fv[4];
#pragma unroll
            for (int r = 0; r < 4; ++r) {
                const int i = ty * 4 + r;
                const int o = i * DC + swq8(i, dq) * 4;
                fa[r] = *(const float4*)&Al[o];
                fb[r] = *(const float4*)&Bl[o];
                fv[r] = *(const float4*)&Vl[o];
            }
#pragma unroll
            for (int rj = 0; rj < 8; ++rj) {
                const int j = tx * 8 + rj;
                const float4 f = *(const float4*)&Fl[j * DC + swq8(j, dq) * 4];
                const float4 f2 = make_float4(f.x * f.x, f.y * f.y, f.z * f.z, f.w * f.w);
#pragma unroll
                for (int ri = 0; ri < 4; ++ri) {
                    const float t0 = fmaf(f2.x, fv[ri].x, fmaf(fb[ri].x, f.x, fa[ri].x));
                    const float t1 = fmaf(f2.y, fv[ri].y, fmaf(fb[ri].y, f.y, fa[ri].y));
                    const float t2 = fmaf(f2.z, fv[ri].z, fmaf(fb[ri].z, f.z, fa[ri].z));
                    const float t3 = fmaf(f2.w, fv[ri].w, fmaf(fb[ri].w, f.w, fa[ri].w));
                    s1[ri][rj] += (t0 + t1) + (t2 + t3);
                    s2[ri][rj] += (fabsf(t0) + fabsf(t1)) + (fabsf(t2) + fabsf(t3));
                }
            }
        }
    }

    // epilogue: masked, row-normalized weighting (linear in s1/s2 -> d-split safe)
    float csum = 0.f;
#pragma unroll
    for (int ri = 0; ri < 4; ++ri) {
        const int ti  = (int)tgt[i0 + ty * 4 + ri];
        const int cnt = counts[ti];
        const float wp = 1.0f / (float)cnt;
        const float wn = 1.0f / (float)(NN - cnt);
#pragma unroll
        for (int rj = 0; rj < 8; ++rj) {
            const int tj = (int)tgt[j0 + tx * 8 + rj];
            const float lp = 0.5f * (s2[ri][rj] + s1[ri][rj]);
            const float ln = 0.5f * (s2[ri][rj] - s1[ri][rj]);
            csum += (ti == tj) ? lp * wp : ln * wn;
        }
    }

    // deterministic reduction: wave shuffle, then 4 wave results via LDS
#pragma unroll
    for (int off = 32; off > 0; off >>= 1) csum += __shfl_down(csum, off);
    __syncthreads();
    if (lane == 0) Al[w] = csum;
    __syncthreads();
    if (tid == 0) partials[bid] = (Al[0] + Al[1]) + (Al[2] + Al[3]);
}

__global__ __launch_bounds__(256) void finalize_kernel(const float* __restrict__ partials,
                                                       float* __restrict__ out) {
    __shared__ float red[256];
    const int tid = threadIdx.x;
    red[tid] = partials[tid] + partials[tid + 256];
    __syncthreads();
    for (int s = 128; s > 0; s >>= 1) {
        if (tid < s) red[tid] += red[tid + s];
        __syncthreads();
    }
    if (tid == 0) out[0] = red[0] * (1.0f / (float)NN);
}

extern "C" void kernel_launch(void* const* d_in, const int* in_sizes, int n_in,
                              void* d_out, int out_size, void* d_ws, size_t ws_size,
                              hipStream_t stream) {
    const float* fm_s    = (const float*)d_in[0];
    const float* fm_t    = (const float*)d_in[1];
    const float* lv      = (const float*)d_in[2];
    const long long* tgt = (const long long*)d_in[3];
    // fusion_true (d_in[4]) == 0 path implemented

    int*   counts   = (int*)d_ws;
    float* partials = (float*)((char*)d_ws + 64);

    hipLaunchKernelGGL(count_kernel, dim3(1), dim3(256), 0, stream, tgt, counts);
    hipLaunchKernelGGL(pair_kernel, dim3(NBLK), dim3(256), 0, stream,
                       fm_s, fm_t, lv, tgt, counts, partials);
    hipLaunchKernelGGL(finalize_kernel, dim3(1), dim3(256), 0, stream,
                       partials, (float*)d_out);
}